// Round 5
// baseline (336.218 us; speedup 1.0000x reference)
//
#include <hip/hip_runtime.h>

#define NR 128        // dst nodes per bucket
#define PART_CH 4096  // edges per partition/count block
typedef unsigned short ushortT;
typedef __attribute__((ext_vector_type(8))) short short8;
typedef __attribute__((ext_vector_type(4))) float float4v;
typedef __attribute__((ext_vector_type(2))) float float2v;

__device__ __forceinline__ unsigned short f32_to_bf16_rne(float f) {
    unsigned u = __float_as_uint(f);
    unsigned r = (u + 0x7fffu + ((u >> 16) & 1u)) >> 16;
    return (unsigned short)r;
}

__device__ __forceinline__ unsigned char f32_to_fp8(float f) {
    return (unsigned char)(__builtin_amdgcn_cvt_pk_fp8_f32(f, f, 0, false) & 0xff);
}

__device__ __forceinline__ void accum8(float* acc, uint4 v) {
    unsigned u[4] = {v.x, v.y, v.z, v.w};
#pragma unroll
    for (int q = 0; q < 4; q++) {
        acc[2 * q]     += __uint_as_float(u[q] << 16);
        acc[2 * q + 1] += __uint_as_float(u[q] & 0xffff0000u);
    }
}

// 32 fp8 bytes (two uint4, lane's contiguous permuted slice) -> ag[32]
__device__ __forceinline__ void accum32_fp8(float* ag, uint4 A, uint4 B) {
    unsigned w[8] = {A.x, A.y, A.z, A.w, B.x, B.y, B.z, B.w};
#pragma unroll
    for (int m = 0; m < 8; m++) {
        float2v lo = __builtin_amdgcn_cvt_pk_f32_fp8(w[m], false);
        float2v hi = __builtin_amdgcn_cvt_pk_f32_fp8(w[m], true);
        ag[4 * m + 0] += lo.x;
        ag[4 * m + 1] += lo.y;
        ag[4 * m + 2] += hi.x;
        ag[4 * m + 3] += hi.y;
    }
}

// ---------------- CSR build: bucketed counting sort ----------------

__launch_bounds__(256)
__global__ void bucket_count(const int* __restrict__ dst, int* __restrict__ bcnt, int E, int NB) {
    __shared__ int h[1024];
    int t = threadIdx.x;
    for (int j = t; j < NB; j += 256) h[j] = 0;
    __syncthreads();
    int e0 = blockIdx.x * PART_CH;
    int e1 = min(e0 + PART_CH, E);
    for (int base = e0; base < e1; base += 2048) {
        int idx = base + t;
        int d[8];
        int cnt = 0;
#pragma unroll
        for (int u = 0; u < 8; u++) {
            int e = idx + u * 256;
            if (e < e1) d[cnt++] = dst[e];
        }
        for (int u = 0; u < cnt; u++) atomicAdd(&h[d[u] >> 7], 1);
    }
    __syncthreads();
    for (int j = t; j < NB; j += 256) {
        int v = h[j];
        if (v) atomicAdd(&bcnt[j], v);
    }
}

__launch_bounds__(256)
__global__ void bucket_scan(const int* __restrict__ bcnt, int* __restrict__ bstart,
                            int* __restrict__ gcur, int NB, int E) {
    __shared__ int sh[256];
    int t = threadIdx.x;
    int v[4];
    int tot = 0;
#pragma unroll
    for (int j = 0; j < 4; j++) {
        int idx = t * 4 + j;
        v[j] = (idx < NB) ? bcnt[idx] : 0;
        tot += v[j];
    }
    sh[t] = tot;
    __syncthreads();
    for (int off = 1; off < 256; off <<= 1) {
        int add = (t >= off) ? sh[t - off] : 0;
        __syncthreads();
        sh[t] += add;
        __syncthreads();
    }
    int run = sh[t] - tot;
#pragma unroll
    for (int j = 0; j < 4; j++) {
        int idx = t * 4 + j;
        if (idx < NB) { bstart[idx] = run; gcur[idx] = run; }
        run += v[j];
    }
    if (t == 0) bstart[NB] = E;
}

__launch_bounds__(256)
__global__ void partition_edges(const int* __restrict__ src, const int* __restrict__ dst,
                                int* __restrict__ gcur, unsigned* __restrict__ packed,
                                int E, int NB) {
    __shared__ int hist[1024];
    __shared__ int base[1024];
    int t = threadIdx.x;
    int e0 = blockIdx.x * PART_CH;
    int e1 = min(e0 + PART_CH, E);
    for (int j = t; j < NB; j += 256) hist[j] = 0;
    __syncthreads();
    for (int bb = e0; bb < e1; bb += 2048) {
        int idx = bb + t;
        int d[8];
        int cnt = 0;
#pragma unroll
        for (int u = 0; u < 8; u++) {
            int e = idx + u * 256;
            if (e < e1) d[cnt++] = dst[e];
        }
        for (int u = 0; u < cnt; u++) atomicAdd(&hist[d[u] >> 7], 1);
    }
    __syncthreads();
    for (int j = t; j < NB; j += 256) {
        int h = hist[j];
        base[j] = h ? atomicAdd(&gcur[j], h) : 0;
    }
    __syncthreads();
    for (int j = t; j < NB; j += 256) hist[j] = base[j];
    __syncthreads();
    for (int bb = e0; bb < e1; bb += 2048) {
        int idx = bb + t;
        int d[8], s[8];
        int cnt = 0;
#pragma unroll
        for (int u = 0; u < 8; u++) {
            int e = idx + u * 256;
            if (e < e1) { d[cnt] = dst[e]; s[cnt] = src[e]; cnt++; }
        }
        for (int u = 0; u < cnt; u++) {
            int dd = d[u];
            int pos = atomicAdd(&hist[dd >> 7], 1);
            packed[pos] = (unsigned)s[u] | ((unsigned)(dd & (NR - 1)) << 17);
        }
    }
}

__launch_bounds__(256)
__global__ void bucket_sort(const unsigned* __restrict__ packed, const int* __restrict__ bstart,
                            int* __restrict__ row_start, int* __restrict__ srcs, int N) {
    __shared__ int cnt[NR];
    __shared__ int sc[NR];
    __shared__ int cur[NR];
    int b = blockIdx.x, t = threadIdx.x;
    int nb0 = b * NR;
    int nnode = min(NR, N - nb0);
    int lo = bstart[b], hi = bstart[b + 1];
    if (t < NR) cnt[t] = 0;
    __syncthreads();
    for (int bb = lo; bb < hi; bb += 2048) {
        int idx = bb + t;
        unsigned pk[8];
        int c = 0;
#pragma unroll
        for (int u = 0; u < 8; u++) {
            int e = idx + u * 256;
            if (e < hi) pk[c++] = packed[e];
        }
        for (int u = 0; u < c; u++) atomicAdd(&cnt[pk[u] >> 17], 1);
    }
    __syncthreads();
    if (t < NR) sc[t] = cnt[t];
    __syncthreads();
    for (int off = 1; off < NR; off <<= 1) {
        int add = (t >= off && t < NR) ? sc[t - off] : 0;
        __syncthreads();
        if (t < NR) sc[t] += add;
        __syncthreads();
    }
    if (t < nnode) {
        int s = lo + sc[t] - cnt[t];
        row_start[nb0 + t] = s;
        cur[t] = s;
    }
    if (t == 0 && nb0 + nnode == N) row_start[N] = hi;
    __syncthreads();
    for (int bb = lo; bb < hi; bb += 2048) {
        int idx = bb + t;
        unsigned pk[8];
        int c = 0;
#pragma unroll
        for (int u = 0; u < 8; u++) {
            int e = idx + u * 256;
            if (e < hi) pk[c++] = packed[e];
        }
        for (int u = 0; u < c; u++) {
            int pos = atomicAdd(&cur[pk[u] >> 17], 1);
            srcs[pos] = (int)(pk[u] & 0x1FFFFu);
        }
    }
}

// ---------------- fused prep: x -> bf16 + all weight transposes ----------------
// All W tiles stored as 64-k quarters for 16KB LDS staging:
//   Wt0 (KT=64, 1 stage):  Wt0[col*64 + ((k + 8*col) & 63)]
//   Wt1/Wt2 (KT=256, 4 quarters): Wt[(k>>6)*8192 + col*64 + (((k&63) + 8*col) & 63)]
//   Wa2t (KT=128, 2 quarters):    Wa2t[(k>>6)*8192 + col*64 + (((k&63) + 8*col) & 63)]

__global__ void prep_fused(const float* __restrict__ x, ushortT* __restrict__ xbf, int n4,
                           const float* __restrict__ Wl0, const float* __restrict__ Wr0,
                           const float* __restrict__ Wl1, const float* __restrict__ Wr1,
                           const float* __restrict__ Wl2, const float* __restrict__ Wr2,
                           const float* __restrict__ Wa2,
                           ushortT* __restrict__ Wt0, ushortT* __restrict__ Wt1,
                           ushortT* __restrict__ Wt2, ushortT* __restrict__ Wa2t) {
    int tid0 = blockIdx.x * 256 + threadIdx.x;
    if (tid0 < n4) {
        float4 v = ((const float4*)x)[tid0];
        ushort4 o;
        o.x = f32_to_bf16_rne(v.x);
        o.y = f32_to_bf16_rne(v.y);
        o.z = f32_to_bf16_rne(v.z);
        o.w = f32_to_bf16_rne(v.w);
        ((ushort4*)xbf)[tid0] = o;
        return;
    }
    int tid = tid0 - n4;
    if (tid < 8192) {  // Wt0: KH=32, KT=64
        int col = tid >> 6, k = tid & 63;
        float v = (k < 32) ? Wl0[k * 128 + col] : Wr0[(k - 32) * 128 + col];
        Wt0[col * 64 + ((k + 8 * col) & 63)] = f32_to_bf16_rne(v);
    } else if (tid < 8192 + 32768) {  // Wt1
        int j = tid - 8192;
        int col = j >> 8, k = j & 255;
        float v = (k < 128) ? Wl1[k * 128 + col] : Wr1[(k - 128) * 128 + col];
        Wt1[(k >> 6) * 8192 + col * 64 + (((k & 63) + 8 * col) & 63)] = f32_to_bf16_rne(v);
    } else if (tid < 8192 + 65536) {  // Wt2
        int j = tid - 8192 - 32768;
        int col = j >> 8, k = j & 255;
        float v = (k < 128) ? Wl2[k * 128 + col] : Wr2[(k - 128) * 128 + col];
        Wt2[(k >> 6) * 8192 + col * 64 + (((k & 63) + 8 * col) & 63)] = f32_to_bf16_rne(v);
    } else if (tid < 8192 + 65536 + 16384) {  // Wa2t
        int j = tid - 8192 - 65536;
        int col = j >> 7, k = j & 127;
        Wa2t[(k >> 6) * 8192 + col * 64 + (((k & 63) + 8 * col) & 63)] = f32_to_bf16_rne(Wa2[k * 128 + col]);
    }
}

// ---------------- gather helpers: 3-level pipeline, small register footprint ----------
// fp8 h layout is PERMUTED: feature f stored at byte ((f>>3)&3)*32 + (f>>5)*8 + (f&7),
// so lane q's A-slice (features ks*32+q*8..+8, ks=0..3) is 32 contiguous bytes at q*32.
// Pipeline: src indices prefetched 2 batches ahead (regs), row loads ping-pong 1 batch
// ahead -- the srcs->rowload serial chain never sits on the critical path.
// Batch sized small (2 fp8 / 4 bf16 neighbors) to keep VGPR ~90 (allocator-respected).
// Edge order strictly ascending -> numerics identical to the unfused path.

__device__ __forceinline__ void gather_fp8(const uint4* __restrict__ hp,
                                           const int* __restrict__ srcs,
                                           int lo, int deg, int q, float* ag) {
    if (deg <= 0) return;
    int last = lo + deg - 1;
    int nb = (deg + 1) >> 1;
    int sA0, sA1, sB0, sB1;
    uint4 A[4], B[4];
    sA0 = srcs[lo];
    sA1 = srcs[min(lo + 1, last)];
    sB0 = srcs[min(lo + 2, last)];
    sB1 = srcs[min(lo + 3, last)];
    {
        size_t b0 = (size_t)sA0 * 8 + q * 2;
        size_t b1 = (size_t)sA1 * 8 + q * 2;
        A[0] = hp[b0]; A[1] = hp[b0 + 1];
        A[2] = hp[b1]; A[3] = hp[b1 + 1];
    }
    for (int b = 0; b < nb; b++) {
        if (!(b & 1)) {
            if (b + 1 < nb) {
                size_t b0 = (size_t)sB0 * 8 + q * 2;
                size_t b1 = (size_t)sB1 * 8 + q * 2;
                B[0] = hp[b0]; B[1] = hp[b0 + 1];
                B[2] = hp[b1]; B[3] = hp[b1 + 1];
            }
            if (b + 2 < nb) {
                sA0 = srcs[min(lo + (b + 2) * 2, last)];
                sA1 = srcs[min(lo + (b + 2) * 2 + 1, last)];
            }
            int rem = deg - b * 2;
            accum32_fp8(ag, A[0], A[1]);
            if (rem > 1) accum32_fp8(ag, A[2], A[3]);
        } else {
            if (b + 1 < nb) {
                size_t b0 = (size_t)sA0 * 8 + q * 2;
                size_t b1 = (size_t)sA1 * 8 + q * 2;
                A[0] = hp[b0]; A[1] = hp[b0 + 1];
                A[2] = hp[b1]; A[3] = hp[b1 + 1];
            }
            if (b + 2 < nb) {
                sB0 = srcs[min(lo + (b + 2) * 2, last)];
                sB1 = srcs[min(lo + (b + 2) * 2 + 1, last)];
            }
            int rem = deg - b * 2;
            accum32_fp8(ag, B[0], B[1]);
            if (rem > 1) accum32_fp8(ag, B[2], B[3]);
        }
    }
}

__device__ __forceinline__ void gather_bf16(const uint4* __restrict__ xp,
                                            const int* __restrict__ srcs,
                                            int lo, int deg, int q, float* ag) {
    if (deg <= 0) return;
    int last = lo + deg - 1;
    int nb = (deg + 3) >> 2;
    int sA[4], sB[4];
    uint4 A[4], B[4];
#pragma unroll
    for (int u = 0; u < 4; u++) sA[u] = srcs[min(lo + u, last)];
#pragma unroll
    for (int u = 0; u < 4; u++) sB[u] = srcs[min(lo + 4 + u, last)];
#pragma unroll
    for (int u = 0; u < 4; u++) A[u] = xp[(size_t)sA[u] * 4 + q];
    for (int b = 0; b < nb; b++) {
        if (!(b & 1)) {
            if (b + 1 < nb) {
#pragma unroll
                for (int u = 0; u < 4; u++) B[u] = xp[(size_t)sB[u] * 4 + q];
            }
            if (b + 2 < nb) {
#pragma unroll
                for (int u = 0; u < 4; u++) sA[u] = srcs[min(lo + (b + 2) * 4 + u, last)];
            }
            int rem = deg - b * 4;
#pragma unroll
            for (int u = 0; u < 4; u++)
                if (u < rem) accum8(ag, A[u]);
        } else {
            if (b + 1 < nb) {
#pragma unroll
                for (int u = 0; u < 4; u++) A[u] = xp[(size_t)sA[u] * 4 + q];
            }
            if (b + 2 < nb) {
#pragma unroll
                for (int u = 0; u < 4; u++) sB[u] = srcs[min(lo + (b + 2) * 4 + u, last)];
            }
            int rem = deg - b * 4;
#pragma unroll
            for (int u = 0; u < 4; u++)
                if (u < rem) accum8(ag, B[u]);
        }
    }
}

// ---------------- fused aggregation + MFMA GEMM (BM=64, 64-k W stages) -----------------
// Each lane owns ONE row (wv*16+cid). sW = 16 KB (one 64-k quarter at a time) so
// occupancy is VGPR-limited (~5-6 blocks/CU at ~90 VGPR), not LDS-limited.
// __launch_bounds__(256,2): 256-VGPR budget, allocator lands well under (R4: 76).

__device__ __forceinline__ void stage_copy(ushortT* sW, const ushortT* Wq, int t) {
    const uint4* Wg = (const uint4*)Wq;
    uint4* Ws = (uint4*)sW;
#pragma unroll
    for (int j = 0; j < 4; j++) Ws[t + j * 256] = Wg[t + j * 256];
}

template <int KH, bool IN_FP8>
__device__ __forceinline__ void gemm_agg_body(
        const void* __restrict__ gat, const ushortT* __restrict__ Ah,
        const int* __restrict__ srcs, const int* __restrict__ rs,
        const ushortT* __restrict__ Wt, const float* __restrict__ bias,
        ushortT* __restrict__ outbf, unsigned char* __restrict__ outf8, int n) {
    constexpr int NKS = KH / 32;
    __shared__ __attribute__((aligned(16))) ushortT sW[128 * 64];   // 16 KB stage
    int t = threadIdx.x;
    stage_copy(sW, Wt, t);   // stage 0 issued before gather; latency hidden under it
    int wv = t >> 6, lane = t & 63;
    int q = lane >> 4, cid = lane & 15;
    int row = blockIdx.x * 64 + wv * 16 + cid;
    int rc = min(row, n - 1);

    // ---- register aggregation (mean of neighbor rows, this lane's feature slice)
    float ag[NKS * 8];
#pragma unroll
    for (int j = 0; j < NKS * 8; j++) ag[j] = 0.f;
    int lo = rs[rc], deg = rs[rc + 1] - lo;
    if constexpr (IN_FP8) gather_fp8((const uint4*)gat, srcs, lo, deg, q, ag);
    else                  gather_bf16((const uint4*)gat, srcs, lo, deg, q, ag);
    float inv = 1.0f / (float)max(deg, 1);
    short8 am[NKS];
#pragma unroll
    for (int ks = 0; ks < NKS; ks++)
#pragma unroll
        for (int j = 0; j < 8; j++) am[ks][j] = (short)f32_to_bf16_rne(ag[ks * 8 + j] * inv);
    // self-row fragments: issue early so latency hides under MFMA stages 0/1
    short8 ah[NKS];
#pragma unroll
    for (int ks = 0; ks < NKS; ks++)
        ah[ks] = *(const short8*)(Ah + (size_t)rc * KH + ks * 32 + q * 8);
    __syncthreads();   // stage 0 ready

    float4v acc[8];
#pragma unroll
    for (int j = 0; j < 8; j++) acc[j] = (float4v){0.f, 0.f, 0.f, 0.f};
    int pbase = q * 8 + 8 * cid;
    if constexpr (KH == 32) {
        {
            int p = pbase & 63;
#pragma unroll
            for (int j = 0; j < 8; ++j) {
                short8 b = *(const short8*)(sW + (j * 16 + cid) * 64 + p);
                acc[j] = __builtin_amdgcn_mfma_f32_16x16x32_bf16(am[0], b, acc[j], 0, 0, 0);
            }
        }
        {
            int p = (32 + pbase) & 63;
#pragma unroll
            for (int j = 0; j < 8; ++j) {
                short8 b = *(const short8*)(sW + (j * 16 + cid) * 64 + p);
                acc[j] = __builtin_amdgcn_mfma_f32_16x16x32_bf16(ah[0], b, acc[j], 0, 0, 0);
            }
        }
    } else {
#pragma unroll
        for (int st = 0; st < 4; st++) {
            if (st > 0) {
                __syncthreads();
                stage_copy(sW, Wt + st * 8192, t);
                __syncthreads();
            }
#pragma unroll
            for (int ksl = 0; ksl < 2; ksl++) {
                short8 a = (st < 2) ? am[st * 2 + ksl] : ah[(st - 2) * 2 + ksl];
                int p = (ksl * 32 + pbase) & 63;
#pragma unroll
                for (int j = 0; j < 8; ++j) {
                    short8 b = *(const short8*)(sW + (j * 16 + cid) * 64 + p);
                    acc[j] = __builtin_amdgcn_mfma_f32_16x16x32_bf16(a, b, acc[j], 0, 0, 0);
                }
            }
        }
    }
    // epilogue: relu + bias; dual-write bf16 (linear) + fp8 (permuted)
    float bo[8];
#pragma unroll
    for (int j = 0; j < 8; ++j) bo[j] = bias[j * 16 + cid];
    int orow = blockIdx.x * 64 + wv * 16 + q * 4;
#pragma unroll
    for (int rr = 0; rr < 4; ++rr) {
        int r = orow + rr;
        if (r < n) {
#pragma unroll
            for (int j = 0; j < 8; ++j) {
                int col = j * 16 + cid;
                float v = fmaxf(acc[j][rr] + bo[j], 0.f);
                outbf[(size_t)r * 128 + col] = f32_to_bf16_rne(v);
                int pc = ((col >> 3) & 3) * 32 + ((col >> 5) << 3) + (col & 7);
                outf8[(size_t)r * 128 + pc] = f32_to_fp8(v);
            }
        }
    }
}

__launch_bounds__(256, 2)
__global__ void gemm_agg32(const void* __restrict__ gat, const ushortT* __restrict__ Ah,
                           const int* __restrict__ srcs, const int* __restrict__ rs,
                           const ushortT* __restrict__ Wt, const float* __restrict__ bias,
                           ushortT* __restrict__ outbf, unsigned char* __restrict__ outf8, int n) {
    gemm_agg_body<32, false>(gat, Ah, srcs, rs, Wt, bias, outbf, outf8, n);
}

__launch_bounds__(256, 2)
__global__ void gemm_agg128(const void* __restrict__ gat, const ushortT* __restrict__ Ah,
                            const int* __restrict__ srcs, const int* __restrict__ rs,
                            const ushortT* __restrict__ Wt, const float* __restrict__ bias,
                            ushortT* __restrict__ outbf, unsigned char* __restrict__ outf8, int n) {
    gemm_agg_body<128, true>(gat, Ah, srcs, rs, Wt, bias, outbf, outf8, n);
}

// ---- layer-2 variant: fused aggregation + GEMM + d1/d3 epilogue + aux-head MLP --------

__launch_bounds__(256, 2)
__global__ void gemm_agg_fin(const void* __restrict__ gat, const ushortT* __restrict__ Ah,
                             const int* __restrict__ srcs, const int* __restrict__ rs,
                             const ushortT* __restrict__ Wt, const float* __restrict__ bias,
                             const float* __restrict__ Wfc, const float* __restrict__ bfc,
                             const ushortT* __restrict__ Wa2t, const float* __restrict__ Wa1,
                             const float* __restrict__ ba1, const float* __restrict__ ba2,
                             const float* __restrict__ Wao, const float* __restrict__ bao,
                             float* __restrict__ fin, int n) {
    __shared__ __attribute__((aligned(16))) ushortT sW[128 * 64];   // 16 KB stage
    __shared__ float sD1[64], sD3[64];
    __shared__ float sWa1a[128], sWa1b[128], sBa1[128];
    int t = threadIdx.x;
    stage_copy(sW, Wt, t);
    if (t < 128) { sWa1a[t] = Wa1[t]; sWa1b[t] = Wa1[128 + t]; sBa1[t] = ba1[t]; }
    int wv = t >> 6, lane = t & 63;
    int q = lane >> 4, cid = lane & 15;
    int row = blockIdx.x * 64 + wv * 16 + cid;
    int rc = min(row, n - 1);

    float ag[32];
#pragma unroll
    for (int j = 0; j < 32; j++) ag[j] = 0.f;
    int lo = rs[rc], deg = rs[rc + 1] - lo;
    gather_fp8((const uint4*)gat, srcs, lo, deg, q, ag);
    float inv = 1.0f / (float)max(deg, 1);
    short8 am[4];
#pragma unroll
    for (int ks = 0; ks < 4; ks++)
#pragma unroll
        for (int j = 0; j < 8; j++) am[ks][j] = (short)f32_to_bf16_rne(ag[ks * 8 + j] * inv);
    short8 ah[4];
#pragma unroll
    for (int ks = 0; ks < 4; ks++)
        ah[ks] = *(const short8*)(Ah + (size_t)rc * 128 + ks * 32 + q * 8);
    __syncthreads();   // stage 0 ready

    float4v acc[8];
#pragma unroll
    for (int j = 0; j < 8; j++) acc[j] = (float4v){0.f, 0.f, 0.f, 0.f};
    int pbase = q * 8 + 8 * cid;
#pragma unroll
    for (int st = 0; st < 4; st++) {
        if (st > 0) {
            __syncthreads();
            stage_copy(sW, Wt + st * 8192, t);
            __syncthreads();
        }
#pragma unroll
        for (int ksl = 0; ksl < 2; ksl++) {
            short8 a = (st < 2) ? am[st * 2 + ksl] : ah[(st - 2) * 2 + ksl];
            int p = (ksl * 32 + pbase) & 63;
#pragma unroll
            for (int j = 0; j < 8; ++j) {
                short8 b = *(const short8*)(sW + (j * 16 + cid) * 64 + p);
                acc[j] = __builtin_amdgcn_mfma_f32_16x16x32_bf16(a, b, acc[j], 0, 0, 0);
            }
        }
    }

    // ---- epilogue: d1/d3 -> fin[:,0], fin[:,2] + block-local LDS
    float bo[8], w1[8], w3[8];
#pragma unroll
    for (int j = 0; j < 8; ++j) {
        int col = j * 16 + cid;
        bo[j] = bias[col];
        w1[j] = Wfc[col * 3 + 0];
        w3[j] = Wfc[col * 3 + 2];
    }
    float bfc0 = bfc[0], bfc2 = bfc[2];
#pragma unroll
    for (int rr = 0; rr < 4; ++rr) {
        float p1 = 0.f, p3 = 0.f;
#pragma unroll
        for (int j = 0; j < 8; ++j) {
            float v = fmaxf(acc[j][rr] + bo[j], 0.f);
            p1 += v * w1[j];
            p3 += v * w3[j];
        }
        p1 += __shfl_xor(p1, 1, 64); p3 += __shfl_xor(p3, 1, 64);
        p1 += __shfl_xor(p1, 2, 64); p3 += __shfl_xor(p3, 2, 64);
        p1 += __shfl_xor(p1, 4, 64); p3 += __shfl_xor(p3, 4, 64);
        p1 += __shfl_xor(p1, 8, 64); p3 += __shfl_xor(p3, 8, 64);
        if (cid == 0) {
            int rowl = wv * 16 + q * 4 + rr;
            float d1 = p1 + bfc0, d3 = p3 + bfc2;
            sD1[rowl] = d1;
            sD3[rowl] = d3;
            int r = blockIdx.x * 64 + rowl;
            if (r < n) {
                fin[(size_t)r * 3 + 0] = d1;
                fin[(size_t)r * 3 + 2] = d3;
            }
        }
    }
    __syncthreads();   // sD ready; everyone done reading sW stage 3

    // ---- aux head: a1 built in registers + a2 MFMA (2 x 64-k stages) -> fin[:,1]
    int rl = wv * 16 + cid;
    float d1a = sD1[rl], d3a = sD3[rl];
    float4v hacc[8];
#pragma unroll
    for (int j = 0; j < 8; j++) hacc[j] = (float4v){0.f, 0.f, 0.f, 0.f};
#pragma unroll
    for (int hs = 0; hs < 2; hs++) {
        if (hs > 0) __syncthreads();
        stage_copy(sW, Wa2t + hs * 8192, t);
        __syncthreads();
#pragma unroll
        for (int ksl = 0; ksl < 2; ++ksl) {
            int k0 = hs * 64 + ksl * 32 + q * 8;
            short8 a0;
#pragma unroll
            for (int j = 0; j < 8; ++j) {
                int k = k0 + j;
                float v0 = fmaxf(fmaf(d1a, sWa1a[k], fmaf(d3a, sWa1b[k], sBa1[k])), 0.f);
                a0[j] = (short)f32_to_bf16_rne(v0);
            }
            int p = (ksl * 32 + pbase) & 63;
#pragma unroll
            for (int j = 0; j < 8; ++j) {
                short8 b = *(const short8*)(sW + (j * 16 + cid) * 64 + p);
                hacc[j] = __builtin_amdgcn_mfma_f32_16x16x32_bf16(a0, b, hacc[j], 0, 0, 0);
            }
        }
    }
    float b2[8], wo[8];
#pragma unroll
    for (int j = 0; j < 8; ++j) {
        int col = j * 16 + cid;
        b2[j] = ba2[col];
        wo[j] = Wao[col];
    }
    float bao0 = bao[0];
#pragma unroll
    for (int rr = 0; rr < 4; ++rr) {
        float s = 0.f;
#pragma unroll
        for (int j = 0; j < 8; ++j) s += fmaxf(hacc[j][rr] + b2[j], 0.f) * wo[j];
        s += __shfl_xor(s, 1, 64);
        s += __shfl_xor(s, 2, 64);
        s += __shfl_xor(s, 4, 64);
        s += __shfl_xor(s, 8, 64);
        int r = blockIdx.x * 64 + wv * 16 + q * 4 + rr;
        if (cid == 0 && r < n) fin[(size_t)r * 3 + 1] = s + bao0;
    }
}

// ---------------- per-graph mean pool ----------------

__global__ void pool_kernel(const float* __restrict__ fin, const int* __restrict__ batch,
                            float* __restrict__ out, int n) {
    int g = blockIdx.x, t = threadIdx.x;
    int lo = 0, hi = n;
    while (lo < hi) { int mid = (lo + hi) >> 1; if (batch[mid] < g) lo = mid + 1; else hi = mid; }
    int start = lo;
    lo = 0; hi = n;
    while (lo < hi) { int mid = (lo + hi) >> 1; if (batch[mid] < g + 1) lo = mid + 1; else hi = mid; }
    int end = lo;
    float s0 = 0.f, s1 = 0.f, s2 = 0.f;
    for (int i = start + t; i < end; i += 256) {
        s0 += fin[(size_t)i * 3 + 0];
        s1 += fin[(size_t)i * 3 + 1];
        s2 += fin[(size_t)i * 3 + 2];
    }
    __shared__ float r0[256], r1[256], r2[256];
    r0[t] = s0; r1[t] = s1; r2[t] = s2;
    __syncthreads();
    for (int off = 128; off > 0; off >>= 1) {
        if (t < off) { r0[t] += r0[t + off]; r1[t] += r1[t + off]; r2[t] += r2[t + off]; }
        __syncthreads();
    }
    if (t == 0) {
        float c = (float)max(end - start, 1);
        out[g * 3 + 0] = r0[0] / c;
        out[g * 3 + 1] = r1[0] / c;
        out[g * 3 + 2] = r2[0] / c;
    }
}

// ---------------- launch ----------------

extern "C" void kernel_launch(void* const* d_in, const int* in_sizes, int n_in,
                              void* d_out, int out_size, void* d_ws, size_t ws_size,
                              hipStream_t stream) {
    const float* x    = (const float*)d_in[0];
    const int*   ei   = (const int*)d_in[1];
    const int*   batch= (const int*)d_in[2];
    const float* Wl0  = (const float*)d_in[3];
    const float* bl0  = (const float*)d_in[4];
    const float* Wr0  = (const float*)d_in[5];
    const float* Wl1  = (const float*)d_in[6];
    const float* bl1  = (const float*)d_in[7];
    const float* Wr1  = (const float*)d_in[8];
    const float* Wl2  = (const float*)d_in[9];
    const float* bl2  = (const float*)d_in[10];
    const float* Wr2  = (const float*)d_in[11];
    const float* Wfc  = (const float*)d_in[12];
    const float* bfc  = (const float*)d_in[13];
    const float* Wa1  = (const float*)d_in[14];
    const float* ba1  = (const float*)d_in[15];
    const float* Wa2  = (const float*)d_in[16];
    const float* ba2  = (const float*)d_in[17];
    const float* Wao  = (const float*)d_in[18];
    const float* bao  = (const float*)d_in[19];

    const int N = in_sizes[0] / 32;
    const int E = in_sizes[1] / 2;
    const int G = out_size / 3;
    const int* src = ei;
    const int* dst = ei + E;
    float* out = (float*)d_out;
    const int NB = (N + NR - 1) / NR;

    char* p = (char*)d_ws;
    auto carve = [&](size_t bytes) {
        void* r = (void*)p;
        p += (bytes + 255) & ~(size_t)255;
        return r;
    };
    int*           bcnt     = (int*)carve((size_t)NB * 4);
    int*           bstart   = (int*)carve((size_t)(NB + 1) * 4);
    int*           gcur     = (int*)carve((size_t)NB * 4);
    int*           row_start= (int*)carve((size_t)(N + 1) * 4);
    unsigned*      packed   = (unsigned*)carve((size_t)E * 4);
    int*           srcs     = (int*)carve((size_t)E * 4);
    ushortT*       xbf      = (ushortT*)carve((size_t)N * 32 * 2);
    ushortT*       hbf0     = (ushortT*)carve((size_t)N * 128 * 2);
    ushortT*       hbf1     = (ushortT*)carve((size_t)N * 128 * 2);
    unsigned char* hf8_0    = (unsigned char*)carve((size_t)N * 128);
    unsigned char* hf8_1    = (unsigned char*)carve((size_t)N * 128);
    float*         fin      = (float*)carve((size_t)N * 3 * 4);
    ushortT*       Wt0      = (ushortT*)carve((size_t)128 * 64 * 2);
    ushortT*       Wt1      = (ushortT*)carve((size_t)128 * 256 * 2);
    ushortT*       Wt2      = (ushortT*)carve((size_t)128 * 256 * 2);
    ushortT*       Wa2t     = (ushortT*)carve((size_t)128 * 128 * 2);

    const int gemm_grid = (N + 63) / 64;
    const int part_grid = (E + PART_CH - 1) / PART_CH;
    const int n4 = N * 32 / 4;

    // fused input/weight prep
    prep_fused<<<(n4 + 90112 + 255) / 256, 256, 0, stream>>>(
        x, xbf, n4, Wl0, Wr0, Wl1, Wr1, Wl2, Wr2, Wa2, Wt0, Wt1, Wt2, Wa2t);

    // CSR build
    hipMemsetAsync(bcnt, 0, (size_t)NB * 4, stream);
    bucket_count<<<part_grid, 256, 0, stream>>>(dst, bcnt, E, NB);
    bucket_scan<<<1, 256, 0, stream>>>(bcnt, bstart, gcur, NB, E);
    partition_edges<<<part_grid, 256, 0, stream>>>(src, dst, gcur, packed, E, NB);
    bucket_sort<<<NB, 256, 0, stream>>>(packed, bstart, row_start, srcs, N);

    // layer 0 (KH=32): fused bf16 gather + GEMM; dual-write h0 (bf16 + permuted fp8)
    gemm_agg32<<<gemm_grid, 256, 0, stream>>>(
        (const void*)xbf, xbf, srcs, row_start, Wt0, bl0, hbf0, hf8_0, N);
    // layer 1 (KH=128): fused fp8 gather + GEMM; dual-write h1
    gemm_agg128<<<gemm_grid, 256, 0, stream>>>(
        (const void*)hf8_0, hbf0, srcs, row_start, Wt1, bl1, hbf1, hf8_1, N);
    // layer 2 (KH=128): fused fp8 gather + GEMM + d1/d3 epilogue + aux head -> fin
    gemm_agg_fin<<<gemm_grid, 256, 0, stream>>>(
        (const void*)hf8_1, hbf1, srcs, row_start, Wt2, bl2, Wfc, bfc,
        Wa2t, Wa1, ba1, ba2, Wao, bao, fin, N);

    // per-graph mean pool
    pool_kernel<<<G, 256, 0, stream>>>(fin, batch, out, N);
}

// Round 6
// 334.930 us; speedup vs baseline: 1.0038x; 1.0038x over previous
//
#include <hip/hip_runtime.h>

#define NR 128        // dst nodes per bucket
#define PART_CH 4096  // edges per partition/count block
typedef unsigned short ushortT;
typedef __attribute__((ext_vector_type(8))) short short8;
typedef __attribute__((ext_vector_type(4))) float float4v;
typedef __attribute__((ext_vector_type(2))) float float2v;

__device__ __forceinline__ unsigned short f32_to_bf16_rne(float f) {
    unsigned u = __float_as_uint(f);
    unsigned r = (u + 0x7fffu + ((u >> 16) & 1u)) >> 16;
    return (unsigned short)r;
}

__device__ __forceinline__ unsigned char f32_to_fp8(float f) {
    return (unsigned char)(__builtin_amdgcn_cvt_pk_fp8_f32(f, f, 0, false) & 0xff);
}

__device__ __forceinline__ void accum8(float* acc, uint4 v) {
    unsigned u[4] = {v.x, v.y, v.z, v.w};
#pragma unroll
    for (int q = 0; q < 4; q++) {
        acc[2 * q]     += __uint_as_float(u[q] << 16);
        acc[2 * q + 1] += __uint_as_float(u[q] & 0xffff0000u);
    }
}

// 32 fp8 bytes (two uint4, lane's contiguous permuted slice) -> ag[32]
__device__ __forceinline__ void accum32_fp8(float* ag, uint4 A, uint4 B) {
    unsigned w[8] = {A.x, A.y, A.z, A.w, B.x, B.y, B.z, B.w};
#pragma unroll
    for (int m = 0; m < 8; m++) {
        float2v lo = __builtin_amdgcn_cvt_pk_f32_fp8(w[m], false);
        float2v hi = __builtin_amdgcn_cvt_pk_f32_fp8(w[m], true);
        ag[4 * m + 0] += lo.x;
        ag[4 * m + 1] += lo.y;
        ag[4 * m + 2] += hi.x;
        ag[4 * m + 3] += hi.y;
    }
}

// ---------------- CSR build: bucketed counting sort ----------------

__launch_bounds__(256)
__global__ void bucket_count(const int* __restrict__ dst, int* __restrict__ bcnt, int E, int NB) {
    __shared__ int h[1024];
    int t = threadIdx.x;
    for (int j = t; j < NB; j += 256) h[j] = 0;
    __syncthreads();
    int e0 = blockIdx.x * PART_CH;
    int e1 = min(e0 + PART_CH, E);
    for (int base = e0; base < e1; base += 2048) {
        int idx = base + t;
        int d[8];
        int cnt = 0;
#pragma unroll
        for (int u = 0; u < 8; u++) {
            int e = idx + u * 256;
            if (e < e1) d[cnt++] = dst[e];
        }
        for (int u = 0; u < cnt; u++) atomicAdd(&h[d[u] >> 7], 1);
    }
    __syncthreads();
    for (int j = t; j < NB; j += 256) {
        int v = h[j];
        if (v) atomicAdd(&bcnt[j], v);
    }
}

__launch_bounds__(256)
__global__ void bucket_scan(const int* __restrict__ bcnt, int* __restrict__ bstart,
                            int* __restrict__ gcur, int NB, int E) {
    __shared__ int sh[256];
    int t = threadIdx.x;
    int v[4];
    int tot = 0;
#pragma unroll
    for (int j = 0; j < 4; j++) {
        int idx = t * 4 + j;
        v[j] = (idx < NB) ? bcnt[idx] : 0;
        tot += v[j];
    }
    sh[t] = tot;
    __syncthreads();
    for (int off = 1; off < 256; off <<= 1) {
        int add = (t >= off) ? sh[t - off] : 0;
        __syncthreads();
        sh[t] += add;
        __syncthreads();
    }
    int run = sh[t] - tot;
#pragma unroll
    for (int j = 0; j < 4; j++) {
        int idx = t * 4 + j;
        if (idx < NB) { bstart[idx] = run; gcur[idx] = run; }
        run += v[j];
    }
    if (t == 0) bstart[NB] = E;
}

__launch_bounds__(256)
__global__ void partition_edges(const int* __restrict__ src, const int* __restrict__ dst,
                                int* __restrict__ gcur, unsigned* __restrict__ packed,
                                int E, int NB) {
    __shared__ int hist[1024];
    __shared__ int base[1024];
    int t = threadIdx.x;
    int e0 = blockIdx.x * PART_CH;
    int e1 = min(e0 + PART_CH, E);
    for (int j = t; j < NB; j += 256) hist[j] = 0;
    __syncthreads();
    for (int bb = e0; bb < e1; bb += 2048) {
        int idx = bb + t;
        int d[8];
        int cnt = 0;
#pragma unroll
        for (int u = 0; u < 8; u++) {
            int e = idx + u * 256;
            if (e < e1) d[cnt++] = dst[e];
        }
        for (int u = 0; u < cnt; u++) atomicAdd(&hist[d[u] >> 7], 1);
    }
    __syncthreads();
    for (int j = t; j < NB; j += 256) {
        int h = hist[j];
        base[j] = h ? atomicAdd(&gcur[j], h) : 0;
    }
    __syncthreads();
    for (int j = t; j < NB; j += 256) hist[j] = base[j];
    __syncthreads();
    for (int bb = e0; bb < e1; bb += 2048) {
        int idx = bb + t;
        int d[8], s[8];
        int cnt = 0;
#pragma unroll
        for (int u = 0; u < 8; u++) {
            int e = idx + u * 256;
            if (e < e1) { d[cnt] = dst[e]; s[cnt] = src[e]; cnt++; }
        }
        for (int u = 0; u < cnt; u++) {
            int dd = d[u];
            int pos = atomicAdd(&hist[dd >> 7], 1);
            packed[pos] = (unsigned)s[u] | ((unsigned)(dd & (NR - 1)) << 17);
        }
    }
}

// Per-bucket counting sort by key = (row<<3) | src_chunk, chunk = src>>14.
// Row lists come out SOURCE-CHUNK-ORDERED: at any instant all lanes/blocks gather
// from the same ~2.1 MB source chunk -> per-XCD L2-resident gather stream.
__launch_bounds__(256)
__global__ void bucket_sort(const unsigned* __restrict__ packed, const int* __restrict__ bstart,
                            int* __restrict__ row_start, int* __restrict__ srcs, int N) {
    __shared__ int cnt[1024];   // -> exclusive prefix in place
    __shared__ int cur[1024];
    __shared__ int psum[256];
    int b = blockIdx.x, t = threadIdx.x;
    int nb0 = b * NR;
    int nnode = min(NR, N - nb0);
    int lo = bstart[b], hi = bstart[b + 1];
#pragma unroll
    for (int j = 0; j < 4; j++) cnt[t + j * 256] = 0;
    __syncthreads();
    for (int bb = lo; bb < hi; bb += 2048) {
        int idx = bb + t;
        unsigned pk[8];
        int c = 0;
#pragma unroll
        for (int u = 0; u < 8; u++) {
            int e = idx + u * 256;
            if (e < hi) pk[c++] = packed[e];
        }
        for (int u = 0; u < c; u++) {
            unsigned s = pk[u] & 0x1FFFFu;
            int key = (int)((pk[u] >> 17) << 3) | (int)(s >> 14);
            atomicAdd(&cnt[key], 1);
        }
    }
    __syncthreads();
    // exclusive scan over 1024: thread t owns keys 4t..4t+3
    int base4 = t * 4;
    int v0 = cnt[base4], v1 = cnt[base4 + 1], v2 = cnt[base4 + 2], v3 = cnt[base4 + 3];
    int s4 = v0 + v1 + v2 + v3;
    psum[t] = s4;
    __syncthreads();
    for (int off = 1; off < 256; off <<= 1) {
        int add = (t >= off) ? psum[t - off] : 0;
        __syncthreads();
        psum[t] += add;
        __syncthreads();
    }
    int run = psum[t] - s4;   // exclusive over 4-groups
    cnt[base4]     = run;
    cnt[base4 + 1] = run + v0;
    cnt[base4 + 2] = run + v0 + v1;
    cnt[base4 + 3] = run + v0 + v1 + v2;
    cur[base4]     = lo + run;
    cur[base4 + 1] = lo + run + v0;
    cur[base4 + 2] = lo + run + v0 + v1;
    cur[base4 + 3] = lo + run + v0 + v1 + v2;
    __syncthreads();
    if (t < nnode) row_start[nb0 + t] = lo + cnt[t << 3];
    if (t == 0 && nb0 + nnode == N) row_start[N] = hi;
    __syncthreads();
    for (int bb = lo; bb < hi; bb += 2048) {
        int idx = bb + t;
        unsigned pk[8];
        int c = 0;
#pragma unroll
        for (int u = 0; u < 8; u++) {
            int e = idx + u * 256;
            if (e < hi) pk[c++] = packed[e];
        }
        for (int u = 0; u < c; u++) {
            unsigned s = pk[u] & 0x1FFFFu;
            int key = (int)((pk[u] >> 17) << 3) | (int)(s >> 14);
            int pos = atomicAdd(&cur[key], 1);
            srcs[pos] = (int)s;
        }
    }
}

// ---------------- fused prep: x -> bf16 + all weight transposes ----------------
// All W tiles stored as 64-k quarters for 16KB LDS staging:
//   Wt0 (KT=64, 1 stage):  Wt0[col*64 + ((k + 8*col) & 63)]
//   Wt1/Wt2 (KT=256, 4 quarters): Wt[(k>>6)*8192 + col*64 + (((k&63) + 8*col) & 63)]
//   Wa2t (KT=128, 2 quarters):    Wa2t[(k>>6)*8192 + col*64 + (((k&63) + 8*col) & 63)]

__global__ void prep_fused(const float* __restrict__ x, ushortT* __restrict__ xbf, int n4,
                           const float* __restrict__ Wl0, const float* __restrict__ Wr0,
                           const float* __restrict__ Wl1, const float* __restrict__ Wr1,
                           const float* __restrict__ Wl2, const float* __restrict__ Wr2,
                           const float* __restrict__ Wa2,
                           ushortT* __restrict__ Wt0, ushortT* __restrict__ Wt1,
                           ushortT* __restrict__ Wt2, ushortT* __restrict__ Wa2t) {
    int tid0 = blockIdx.x * 256 + threadIdx.x;
    if (tid0 < n4) {
        float4 v = ((const float4*)x)[tid0];
        ushort4 o;
        o.x = f32_to_bf16_rne(v.x);
        o.y = f32_to_bf16_rne(v.y);
        o.z = f32_to_bf16_rne(v.z);
        o.w = f32_to_bf16_rne(v.w);
        ((ushort4*)xbf)[tid0] = o;
        return;
    }
    int tid = tid0 - n4;
    if (tid < 8192) {  // Wt0: KH=32, KT=64
        int col = tid >> 6, k = tid & 63;
        float v = (k < 32) ? Wl0[k * 128 + col] : Wr0[(k - 32) * 128 + col];
        Wt0[col * 64 + ((k + 8 * col) & 63)] = f32_to_bf16_rne(v);
    } else if (tid < 8192 + 32768) {  // Wt1
        int j = tid - 8192;
        int col = j >> 8, k = j & 255;
        float v = (k < 128) ? Wl1[k * 128 + col] : Wr1[(k - 128) * 128 + col];
        Wt1[(k >> 6) * 8192 + col * 64 + (((k & 63) + 8 * col) & 63)] = f32_to_bf16_rne(v);
    } else if (tid < 8192 + 65536) {  // Wt2
        int j = tid - 8192 - 32768;
        int col = j >> 8, k = j & 255;
        float v = (k < 128) ? Wl2[k * 128 + col] : Wr2[(k - 128) * 128 + col];
        Wt2[(k >> 6) * 8192 + col * 64 + (((k & 63) + 8 * col) & 63)] = f32_to_bf16_rne(v);
    } else if (tid < 8192 + 65536 + 16384) {  // Wa2t
        int j = tid - 8192 - 65536;
        int col = j >> 7, k = j & 127;
        Wa2t[(k >> 6) * 8192 + col * 64 + (((k & 63) + 8 * col) & 63)] = f32_to_bf16_rne(Wa2[k * 128 + col]);
    }
}

// ---------------- gather helpers: 3-level pipeline, small register footprint ----------
// fp8 h layout is PERMUTED: feature f stored at byte ((f>>3)&3)*32 + (f>>5)*8 + (f&7),
// so lane q's A-slice (features ks*32+q*8..+8, ks=0..3) is 32 contiguous bytes at q*32.
// srcs is chunk-sorted (bucket_sort) so these accesses stay in a ~2MB hot set.
// Edge order matches the CSR list order -> deterministic.

__device__ __forceinline__ void gather_fp8(const uint4* __restrict__ hp,
                                           const int* __restrict__ srcs,
                                           int lo, int deg, int q, float* ag) {
    if (deg <= 0) return;
    int last = lo + deg - 1;
    int nb = (deg + 1) >> 1;
    int sA0, sA1, sB0, sB1;
    uint4 A[4], B[4];
    sA0 = srcs[lo];
    sA1 = srcs[min(lo + 1, last)];
    sB0 = srcs[min(lo + 2, last)];
    sB1 = srcs[min(lo + 3, last)];
    {
        size_t b0 = (size_t)sA0 * 8 + q * 2;
        size_t b1 = (size_t)sA1 * 8 + q * 2;
        A[0] = hp[b0]; A[1] = hp[b0 + 1];
        A[2] = hp[b1]; A[3] = hp[b1 + 1];
    }
    for (int b = 0; b < nb; b++) {
        if (!(b & 1)) {
            if (b + 1 < nb) {
                size_t b0 = (size_t)sB0 * 8 + q * 2;
                size_t b1 = (size_t)sB1 * 8 + q * 2;
                B[0] = hp[b0]; B[1] = hp[b0 + 1];
                B[2] = hp[b1]; B[3] = hp[b1 + 1];
            }
            if (b + 2 < nb) {
                sA0 = srcs[min(lo + (b + 2) * 2, last)];
                sA1 = srcs[min(lo + (b + 2) * 2 + 1, last)];
            }
            int rem = deg - b * 2;
            accum32_fp8(ag, A[0], A[1]);
            if (rem > 1) accum32_fp8(ag, A[2], A[3]);
        } else {
            if (b + 1 < nb) {
                size_t b0 = (size_t)sA0 * 8 + q * 2;
                size_t b1 = (size_t)sA1 * 8 + q * 2;
                A[0] = hp[b0]; A[1] = hp[b0 + 1];
                A[2] = hp[b1]; A[3] = hp[b1 + 1];
            }
            if (b + 2 < nb) {
                sB0 = srcs[min(lo + (b + 2) * 2, last)];
                sB1 = srcs[min(lo + (b + 2) * 2 + 1, last)];
            }
            int rem = deg - b * 2;
            accum32_fp8(ag, B[0], B[1]);
            if (rem > 1) accum32_fp8(ag, B[2], B[3]);
        }
    }
}

__device__ __forceinline__ void gather_bf16(const uint4* __restrict__ xp,
                                            const int* __restrict__ srcs,
                                            int lo, int deg, int q, float* ag) {
    if (deg <= 0) return;
    int last = lo + deg - 1;
    int nb = (deg + 3) >> 2;
    int sA[4], sB[4];
    uint4 A[4], B[4];
#pragma unroll
    for (int u = 0; u < 4; u++) sA[u] = srcs[min(lo + u, last)];
#pragma unroll
    for (int u = 0; u < 4; u++) sB[u] = srcs[min(lo + 4 + u, last)];
#pragma unroll
    for (int u = 0; u < 4; u++) A[u] = xp[(size_t)sA[u] * 4 + q];
    for (int b = 0; b < nb; b++) {
        if (!(b & 1)) {
            if (b + 1 < nb) {
#pragma unroll
                for (int u = 0; u < 4; u++) B[u] = xp[(size_t)sB[u] * 4 + q];
            }
            if (b + 2 < nb) {
#pragma unroll
                for (int u = 0; u < 4; u++) sA[u] = srcs[min(lo + (b + 2) * 4 + u, last)];
            }
            int rem = deg - b * 4;
#pragma unroll
            for (int u = 0; u < 4; u++)
                if (u < rem) accum8(ag, A[u]);
        } else {
            if (b + 1 < nb) {
#pragma unroll
                for (int u = 0; u < 4; u++) A[u] = xp[(size_t)sA[u] * 4 + q];
            }
            if (b + 2 < nb) {
#pragma unroll
                for (int u = 0; u < 4; u++) sB[u] = srcs[min(lo + (b + 2) * 4 + u, last)];
            }
            int rem = deg - b * 4;
#pragma unroll
            for (int u = 0; u < 4; u++)
                if (u < rem) accum8(ag, B[u]);
        }
    }
}

// ---------------- fused aggregation + MFMA GEMM (BM=64, 64-k W stages) -----------------

__device__ __forceinline__ void stage_copy(ushortT* sW, const ushortT* Wq, int t) {
    const uint4* Wg = (const uint4*)Wq;
    uint4* Ws = (uint4*)sW;
#pragma unroll
    for (int j = 0; j < 4; j++) Ws[t + j * 256] = Wg[t + j * 256];
}

template <int KH, bool IN_FP8>
__device__ __forceinline__ void gemm_agg_body(
        const void* __restrict__ gat, const ushortT* __restrict__ Ah,
        const int* __restrict__ srcs, const int* __restrict__ rs,
        const ushortT* __restrict__ Wt, const float* __restrict__ bias,
        ushortT* __restrict__ outbf, unsigned char* __restrict__ outf8, int n) {
    constexpr int NKS = KH / 32;
    __shared__ __attribute__((aligned(16))) ushortT sW[128 * 64];   // 16 KB stage
    int t = threadIdx.x;
    stage_copy(sW, Wt, t);   // stage 0 issued before gather; latency hidden under it
    int wv = t >> 6, lane = t & 63;
    int q = lane >> 4, cid = lane & 15;
    int row = blockIdx.x * 64 + wv * 16 + cid;
    int rc = min(row, n - 1);

    // ---- register aggregation (mean of neighbor rows, this lane's feature slice)
    float ag[NKS * 8];
#pragma unroll
    for (int j = 0; j < NKS * 8; j++) ag[j] = 0.f;
    int lo = rs[rc], deg = rs[rc + 1] - lo;
    if constexpr (IN_FP8) gather_fp8((const uint4*)gat, srcs, lo, deg, q, ag);
    else                  gather_bf16((const uint4*)gat, srcs, lo, deg, q, ag);
    float inv = 1.0f / (float)max(deg, 1);
    short8 am[NKS];
#pragma unroll
    for (int ks = 0; ks < NKS; ks++)
#pragma unroll
        for (int j = 0; j < 8; j++) am[ks][j] = (short)f32_to_bf16_rne(ag[ks * 8 + j] * inv);
    // self-row fragments: issue early so latency hides under MFMA stages 0/1
    short8 ah[NKS];
#pragma unroll
    for (int ks = 0; ks < NKS; ks++)
        ah[ks] = *(const short8*)(Ah + (size_t)rc * KH + ks * 32 + q * 8);
    __syncthreads();   // stage 0 ready

    float4v acc[8];
#pragma unroll
    for (int j = 0; j < 8; j++) acc[j] = (float4v){0.f, 0.f, 0.f, 0.f};
    int pbase = q * 8 + 8 * cid;
    if constexpr (KH == 32) {
        {
            int p = pbase & 63;
#pragma unroll
            for (int j = 0; j < 8; ++j) {
                short8 b = *(const short8*)(sW + (j * 16 + cid) * 64 + p);
                acc[j] = __builtin_amdgcn_mfma_f32_16x16x32_bf16(am[0], b, acc[j], 0, 0, 0);
            }
        }
        {
            int p = (32 + pbase) & 63;
#pragma unroll
            for (int j = 0; j < 8; ++j) {
                short8 b = *(const short8*)(sW + (j * 16 + cid) * 64 + p);
                acc[j] = __builtin_amdgcn_mfma_f32_16x16x32_bf16(ah[0], b, acc[j], 0, 0, 0);
            }
        }
    } else {
#pragma unroll
        for (int st = 0; st < 4; st++) {
            if (st > 0) {
                __syncthreads();
                stage_copy(sW, Wt + st * 8192, t);
                __syncthreads();
            }
#pragma unroll
            for (int ksl = 0; ksl < 2; ksl++) {
                short8 a = (st < 2) ? am[st * 2 + ksl] : ah[(st - 2) * 2 + ksl];
                int p = (ksl * 32 + pbase) & 63;
#pragma unroll
                for (int j = 0; j < 8; ++j) {
                    short8 b = *(const short8*)(sW + (j * 16 + cid) * 64 + p);
                    acc[j] = __builtin_amdgcn_mfma_f32_16x16x32_bf16(a, b, acc[j], 0, 0, 0);
                }
            }
        }
    }
    // epilogue: relu + bias; dual-write bf16 (linear) + fp8 (permuted)
    float bo[8];
#pragma unroll
    for (int j = 0; j < 8; ++j) bo[j] = bias[j * 16 + cid];
    int orow = blockIdx.x * 64 + wv * 16 + q * 4;
#pragma unroll
    for (int rr = 0; rr < 4; ++rr) {
        int r = orow + rr;
        if (r < n) {
#pragma unroll
            for (int j = 0; j < 8; ++j) {
                int col = j * 16 + cid;
                float v = fmaxf(acc[j][rr] + bo[j], 0.f);
                outbf[(size_t)r * 128 + col] = f32_to_bf16_rne(v);
                int pc = ((col >> 3) & 3) * 32 + ((col >> 5) << 3) + (col & 7);
                outf8[(size_t)r * 128 + pc] = f32_to_fp8(v);
            }
        }
    }
}

__launch_bounds__(256, 2)
__global__ void gemm_agg32(const void* __restrict__ gat, const ushortT* __restrict__ Ah,
                           const int* __restrict__ srcs, const int* __restrict__ rs,
                           const ushortT* __restrict__ Wt, const float* __restrict__ bias,
                           ushortT* __restrict__ outbf, unsigned char* __restrict__ outf8, int n) {
    gemm_agg_body<32, false>(gat, Ah, srcs, rs, Wt, bias, outbf, outf8, n);
}

__launch_bounds__(256, 2)
__global__ void gemm_agg128(const void* __restrict__ gat, const ushortT* __restrict__ Ah,
                            const int* __restrict__ srcs, const int* __restrict__ rs,
                            const ushortT* __restrict__ Wt, const float* __restrict__ bias,
                            ushortT* __restrict__ outbf, unsigned char* __restrict__ outf8, int n) {
    gemm_agg_body<128, true>(gat, Ah, srcs, rs, Wt, bias, outbf, outf8, n);
}

// ---- layer-2 variant: fused aggregation + GEMM + d1/d3 epilogue + aux-head MLP --------

__launch_bounds__(256, 2)
__global__ void gemm_agg_fin(const void* __restrict__ gat, const ushortT* __restrict__ Ah,
                             const int* __restrict__ srcs, const int* __restrict__ rs,
                             const ushortT* __restrict__ Wt, const float* __restrict__ bias,
                             const float* __restrict__ Wfc, const float* __restrict__ bfc,
                             const ushortT* __restrict__ Wa2t, const float* __restrict__ Wa1,
                             const float* __restrict__ ba1, const float* __restrict__ ba2,
                             const float* __restrict__ Wao, const float* __restrict__ bao,
                             float* __restrict__ fin, int n) {
    __shared__ __attribute__((aligned(16))) ushortT sW[128 * 64];   // 16 KB stage
    __shared__ float sD1[64], sD3[64];
    __shared__ float sWa1a[128], sWa1b[128], sBa1[128];
    int t = threadIdx.x;
    stage_copy(sW, Wt, t);
    if (t < 128) { sWa1a[t] = Wa1[t]; sWa1b[t] = Wa1[128 + t]; sBa1[t] = ba1[t]; }
    int wv = t >> 6, lane = t & 63;
    int q = lane >> 4, cid = lane & 15;
    int row = blockIdx.x * 64 + wv * 16 + cid;
    int rc = min(row, n - 1);

    float ag[32];
#pragma unroll
    for (int j = 0; j < 32; j++) ag[j] = 0.f;
    int lo = rs[rc], deg = rs[rc + 1] - lo;
    gather_fp8((const uint4*)gat, srcs, lo, deg, q, ag);
    float inv = 1.0f / (float)max(deg, 1);
    short8 am[4];
#pragma unroll
    for (int ks = 0; ks < 4; ks++)
#pragma unroll
        for (int j = 0; j < 8; j++) am[ks][j] = (short)f32_to_bf16_rne(ag[ks * 8 + j] * inv);
    short8 ah[4];
#pragma unroll
    for (int ks = 0; ks < 4; ks++)
        ah[ks] = *(const short8*)(Ah + (size_t)rc * 128 + ks * 32 + q * 8);
    __syncthreads();   // stage 0 ready

    float4v acc[8];
#pragma unroll
    for (int j = 0; j < 8; j++) acc[j] = (float4v){0.f, 0.f, 0.f, 0.f};
    int pbase = q * 8 + 8 * cid;
#pragma unroll
    for (int st = 0; st < 4; st++) {
        if (st > 0) {
            __syncthreads();
            stage_copy(sW, Wt + st * 8192, t);
            __syncthreads();
        }
#pragma unroll
        for (int ksl = 0; ksl < 2; ksl++) {
            short8 a = (st < 2) ? am[st * 2 + ksl] : ah[(st - 2) * 2 + ksl];
            int p = (ksl * 32 + pbase) & 63;
#pragma unroll
            for (int j = 0; j < 8; ++j) {
                short8 b = *(const short8*)(sW + (j * 16 + cid) * 64 + p);
                acc[j] = __builtin_amdgcn_mfma_f32_16x16x32_bf16(a, b, acc[j], 0, 0, 0);
            }
        }
    }

    // ---- epilogue: d1/d3 -> fin[:,0], fin[:,2] + block-local LDS
    float bo[8], w1[8], w3[8];
#pragma unroll
    for (int j = 0; j < 8; ++j) {
        int col = j * 16 + cid;
        bo[j] = bias[col];
        w1[j] = Wfc[col * 3 + 0];
        w3[j] = Wfc[col * 3 + 2];
    }
    float bfc0 = bfc[0], bfc2 = bfc[2];
#pragma unroll
    for (int rr = 0; rr < 4; ++rr) {
        float p1 = 0.f, p3 = 0.f;
#pragma unroll
        for (int j = 0; j < 8; ++j) {
            float v = fmaxf(acc[j][rr] + bo[j], 0.f);
            p1 += v * w1[j];
            p3 += v * w3[j];
        }
        p1 += __shfl_xor(p1, 1, 64); p3 += __shfl_xor(p3, 1, 64);
        p1 += __shfl_xor(p1, 2, 64); p3 += __shfl_xor(p3, 2, 64);
        p1 += __shfl_xor(p1, 4, 64); p3 += __shfl_xor(p3, 4, 64);
        p1 += __shfl_xor(p1, 8, 64); p3 += __shfl_xor(p3, 8, 64);
        if (cid == 0) {
            int rowl = wv * 16 + q * 4 + rr;
            float d1 = p1 + bfc0, d3 = p3 + bfc2;
            sD1[rowl] = d1;
            sD3[rowl] = d3;
            int r = blockIdx.x * 64 + rowl;
            if (r < n) {
                fin[(size_t)r * 3 + 0] = d1;
                fin[(size_t)r * 3 + 2] = d3;
            }
        }
    }
    __syncthreads();   // sD ready; everyone done reading sW stage 3

    // ---- aux head: a1 built in registers + a2 MFMA (2 x 64-k stages) -> fin[:,1]
    int rl = wv * 16 + cid;
    float d1a = sD1[rl], d3a = sD3[rl];
    float4v hacc[8];
#pragma unroll
    for (int j = 0; j < 8; j++) hacc[j] = (float4v){0.f, 0.f, 0.f, 0.f};
#pragma unroll
    for (int hs = 0; hs < 2; hs++) {
        if (hs > 0) __syncthreads();
        stage_copy(sW, Wa2t + hs * 8192, t);
        __syncthreads();
#pragma unroll
        for (int ksl = 0; ksl < 2; ++ksl) {
            int k0 = hs * 64 + ksl * 32 + q * 8;
            short8 a0;
#pragma unroll
            for (int j = 0; j < 8; ++j) {
                int k = k0 + j;
                float v0 = fmaxf(fmaf(d1a, sWa1a[k], fmaf(d3a, sWa1b[k], sBa1[k])), 0.f);
                a0[j] = (short)f32_to_bf16_rne(v0);
            }
            int p = (ksl * 32 + pbase) & 63;
#pragma unroll
            for (int j = 0; j < 8; ++j) {
                short8 b = *(const short8*)(sW + (j * 16 + cid) * 64 + p);
                hacc[j] = __builtin_amdgcn_mfma_f32_16x16x32_bf16(a0, b, hacc[j], 0, 0, 0);
            }
        }
    }
    float b2[8], wo[8];
#pragma unroll
    for (int j = 0; j < 8; ++j) {
        int col = j * 16 + cid;
        b2[j] = ba2[col];
        wo[j] = Wao[col];
    }
    float bao0 = bao[0];
#pragma unroll
    for (int rr = 0; rr < 4; ++rr) {
        float s = 0.f;
#pragma unroll
        for (int j = 0; j < 8; ++j) s += fmaxf(hacc[j][rr] + b2[j], 0.f) * wo[j];
        s += __shfl_xor(s, 1, 64);
        s += __shfl_xor(s, 2, 64);
        s += __shfl_xor(s, 4, 64);
        s += __shfl_xor(s, 8, 64);
        int r = blockIdx.x * 64 + wv * 16 + q * 4 + rr;
        if (cid == 0 && r < n) fin[(size_t)r * 3 + 1] = s + bao0;
    }
}

// ---------------- per-graph mean pool ----------------

__global__ void pool_kernel(const float* __restrict__ fin, const int* __restrict__ batch,
                            float* __restrict__ out, int n) {
    int g = blockIdx.x, t = threadIdx.x;
    int lo = 0, hi = n;
    while (lo < hi) { int mid = (lo + hi) >> 1; if (batch[mid] < g) lo = mid + 1; else hi = mid; }
    int start = lo;
    lo = 0; hi = n;
    while (lo < hi) { int mid = (lo + hi) >> 1; if (batch[mid] < g + 1) lo = mid + 1; else hi = mid; }
    int end = lo;
    float s0 = 0.f, s1 = 0.f, s2 = 0.f;
    for (int i = start + t; i < end; i += 256) {
        s0 += fin[(size_t)i * 3 + 0];
        s1 += fin[(size_t)i * 3 + 1];
        s2 += fin[(size_t)i * 3 + 2];
    }
    __shared__ float r0[256], r1[256], r2[256];
    r0[t] = s0; r1[t] = s1; r2[t] = s2;
    __syncthreads();
    for (int off = 128; off > 0; off >>= 1) {
        if (t < off) { r0[t] += r0[t + off]; r1[t] += r1[t + off]; r2[t] += r2[t + off]; }
        __syncthreads();
    }
    if (t == 0) {
        float c = (float)max(end - start, 1);
        out[g * 3 + 0] = r0[0] / c;
        out[g * 3 + 1] = r1[0] / c;
        out[g * 3 + 2] = r2[0] / c;
    }
}

// ---------------- launch ----------------

extern "C" void kernel_launch(void* const* d_in, const int* in_sizes, int n_in,
                              void* d_out, int out_size, void* d_ws, size_t ws_size,
                              hipStream_t stream) {
    const float* x    = (const float*)d_in[0];
    const int*   ei   = (const int*)d_in[1];
    const int*   batch= (const int*)d_in[2];
    const float* Wl0  = (const float*)d_in[3];
    const float* bl0  = (const float*)d_in[4];
    const float* Wr0  = (const float*)d_in[5];
    const float* Wl1  = (const float*)d_in[6];
    const float* bl1  = (const float*)d_in[7];
    const float* Wr1  = (const float*)d_in[8];
    const float* Wl2  = (const float*)d_in[9];
    const float* bl2  = (const float*)d_in[10];
    const float* Wr2  = (const float*)d_in[11];
    const float* Wfc  = (const float*)d_in[12];
    const float* bfc  = (const float*)d_in[13];
    const float* Wa1  = (const float*)d_in[14];
    const float* ba1  = (const float*)d_in[15];
    const float* Wa2  = (const float*)d_in[16];
    const float* ba2  = (const float*)d_in[17];
    const float* Wao  = (const float*)d_in[18];
    const float* bao  = (const float*)d_in[19];

    const int N = in_sizes[0] / 32;
    const int E = in_sizes[1] / 2;
    const int G = out_size / 3;
    const int* src = ei;
    const int* dst = ei + E;
    float* out = (float*)d_out;
    const int NB = (N + NR - 1) / NR;

    char* p = (char*)d_ws;
    auto carve = [&](size_t bytes) {
        void* r = (void*)p;
        p += (bytes + 255) & ~(size_t)255;
        return r;
    };
    int*           bcnt     = (int*)carve((size_t)NB * 4);
    int*           bstart   = (int*)carve((size_t)(NB + 1) * 4);
    int*           gcur     = (int*)carve((size_t)NB * 4);
    int*           row_start= (int*)carve((size_t)(N + 1) * 4);
    unsigned*      packed   = (unsigned*)carve((size_t)E * 4);
    int*           srcs     = (int*)carve((size_t)E * 4);
    ushortT*       xbf      = (ushortT*)carve((size_t)N * 32 * 2);
    ushortT*       hbf0     = (ushortT*)carve((size_t)N * 128 * 2);
    ushortT*       hbf1     = (ushortT*)carve((size_t)N * 128 * 2);
    unsigned char* hf8_0    = (unsigned char*)carve((size_t)N * 128);
    unsigned char* hf8_1    = (unsigned char*)carve((size_t)N * 128);
    float*         fin      = (float*)carve((size_t)N * 3 * 4);
    ushortT*       Wt0      = (ushortT*)carve((size_t)128 * 64 * 2);
    ushortT*       Wt1      = (ushortT*)carve((size_t)128 * 256 * 2);
    ushortT*       Wt2      = (ushortT*)carve((size_t)128 * 256 * 2);
    ushortT*       Wa2t     = (ushortT*)carve((size_t)128 * 128 * 2);

    const int gemm_grid = (N + 63) / 64;
    const int part_grid = (E + PART_CH - 1) / PART_CH;
    const int n4 = N * 32 / 4;

    // fused input/weight prep
    prep_fused<<<(n4 + 90112 + 255) / 256, 256, 0, stream>>>(
        x, xbf, n4, Wl0, Wr0, Wl1, Wr1, Wl2, Wr2, Wa2, Wt0, Wt1, Wt2, Wa2t);

    // CSR build (row lists come out source-chunk-ordered for L2 locality)
    hipMemsetAsync(bcnt, 0, (size_t)NB * 4, stream);
    bucket_count<<<part_grid, 256, 0, stream>>>(dst, bcnt, E, NB);
    bucket_scan<<<1, 256, 0, stream>>>(bcnt, bstart, gcur, NB, E);
    partition_edges<<<part_grid, 256, 0, stream>>>(src, dst, gcur, packed, E, NB);
    bucket_sort<<<NB, 256, 0, stream>>>(packed, bstart, row_start, srcs, N);

    // layer 0 (KH=32): fused bf16 gather + GEMM; dual-write h0 (bf16 + permuted fp8)
    gemm_agg32<<<gemm_grid, 256, 0, stream>>>(
        (const void*)xbf, xbf, srcs, row_start, Wt0, bl0, hbf0, hf8_0, N);
    // layer 1 (KH=128): fused fp8 gather + GEMM; dual-write h1
    gemm_agg128<<<gemm_grid, 256, 0, stream>>>(
        (const void*)hf8_0, hbf0, srcs, row_start, Wt1, bl1, hbf1, hf8_1, N);
    // layer 2 (KH=128): fused fp8 gather + GEMM + d1/d3 epilogue + aux head -> fin
    gemm_agg_fin<<<gemm_grid, 256, 0, stream>>>(
        (const void*)hf8_1, hbf1, srcs, row_start, Wt2, bl2, Wfc, bfc,
        Wa2t, Wa1, ba1, ba2, Wao, bao, fin, N);

    // per-graph mean pool
    pool_kernel<<<G, 256, 0, stream>>>(fin, batch, out, N);
}